// Round 1
// baseline (1774.029 us; speedup 1.0000x reference)
//
#include <hip/hip_runtime.h>
#include <math.h>

#define NB 8
#define NPTS 2048
#define NF 323
#define K 20
#define EPSV 1e-5f
#define SLOPE 0.2f

__device__ __forceinline__ float lrelu(float x){ return x >= 0.f ? x : SLOPE * x; }

__device__ __forceinline__ unsigned fkey(float f){
    unsigned u = __float_as_uint(f);
    return (u & 0x80000000u) ? ~u : (u | 0x80000000u);
}
__device__ __forceinline__ float funkey(unsigned k){
    return (k & 0x80000000u) ? __uint_as_float(k ^ 0x80000000u) : __uint_as_float(~k);
}

// ---- x (B,3,N) -> F (B,N,323) channels [0,3) ----
__global__ void copy_x_kernel(const float* __restrict__ x, float* __restrict__ F){
    int gid = blockIdx.x * 256 + threadIdx.x;
    if (gid >= NB * NPTS) return;
    int b = gid / NPTS, n = gid % NPTS;
    float* dst = F + (size_t)gid * NF;
    #pragma unroll
    for (int c = 0; c < 3; c++) dst[c] = x[((size_t)b * 3 + c) * NPTS + n];
}

// ---- per-point squared norm over first C channels ----
__global__ __launch_bounds__(256) void sqnorm_kernel(const float* __restrict__ F, float* __restrict__ sq, int C){
    int row = blockIdx.x * 4 + (threadIdx.x >> 6);
    int lane = threadIdx.x & 63;
    const float* f = F + (size_t)row * NF;
    float s = 0.f;
    for (int c = lane; c < C; c += 64){ float t = f[c]; s += t * t; }
    #pragma unroll
    for (int off = 32; off; off >>= 1) s += __shfl_xor(s, off);
    if (lane == 0) sq[row] = s;
}

// ---- inv-dist tile: D = 2*dot - sq_i - sq_j  (64x64 tile, 256 thr, 4x4 micro) ----
__global__ __launch_bounds__(256) void dist_kernel(const float* __restrict__ F, const float* __restrict__ sq,
                                                   float* __restrict__ dist, int C, int chunk_base){
    __shared__ float Fi[64][17], Fj[64][17];
    int tid = threadIdx.x;
    int tj = tid & 15, ti = tid >> 4;
    int row0 = chunk_base + blockIdx.y * 64;         // global flat row (b*2048+i)
    int b = row0 >> 11;
    int i0 = row0 & 2047;
    int j0 = blockIdx.x * 64;
    const float* Fb = F + ((size_t)b * NPTS) * NF;
    float acc[4][4];
    #pragma unroll
    for (int q = 0; q < 4; q++)
        #pragma unroll
        for (int p = 0; p < 4; p++) acc[q][p] = 0.f;

    for (int c0 = 0; c0 < C; c0 += 16){
        #pragma unroll
        for (int q = 0; q < 4; q++){
            int r = (tid >> 4) + q * 16;
            int c = tid & 15;
            int cc = c0 + c;
            float a = 0.f, bb = 0.f;
            if (cc < C){
                a  = Fb[(size_t)(i0 + r) * NF + cc];
                bb = Fb[(size_t)(j0 + r) * NF + cc];
            }
            Fi[r][c] = a; Fj[r][c] = bb;
        }
        __syncthreads();
        #pragma unroll
        for (int c = 0; c < 16; c++){
            float a0[4], b0[4];
            #pragma unroll
            for (int q = 0; q < 4; q++){ a0[q] = Fi[ti * 4 + q][c]; b0[q] = Fj[tj * 4 + q][c]; }
            #pragma unroll
            for (int q = 0; q < 4; q++)
                #pragma unroll
                for (int p = 0; p < 4; p++) acc[q][p] += a0[q] * b0[p];
        }
        __syncthreads();
    }
    #pragma unroll
    for (int q = 0; q < 4; q++){
        float si = sq[row0 + ti * 4 + q];
        float* drow = dist + (size_t)(row0 - chunk_base + ti * 4 + q) * NPTS;
        #pragma unroll
        for (int p = 0; p < 4; p++){
            int j = j0 + tj * 4 + p;
            float sj = sq[(b << 11) + j];
            drow[j] = 2.f * acc[q][p] - si - sj;
        }
    }
}

// ---- top-21 per row (wave per row); tie: larger val, then smaller index; drop first (self) ----
__global__ __launch_bounds__(256) void topk_kernel(const float* __restrict__ dist, int* __restrict__ idxo, int chunk_base){
    int lrow = blockIdx.x * 4 + (threadIdx.x >> 6);
    int lane = threadIdx.x & 63;
    const float* D = dist + (size_t)lrow * NPTS;
    float vals[32];
    #pragma unroll
    for (int t = 0; t < 32; t++) vals[t] = D[t * 64 + lane];
    int* out = idxo + (size_t)(chunk_base + lrow) * K;
    for (int it = 0; it < K + 1; it++){
        float bv = vals[0]; int bt = 0;
        #pragma unroll
        for (int t = 1; t < 32; t++){ if (vals[t] > bv){ bv = vals[t]; bt = t; } }
        int bcol = bt * 64 + lane;
        #pragma unroll
        for (int off = 1; off < 64; off <<= 1){
            float ov = __shfl_xor(bv, off);
            int   oc = __shfl_xor(bcol, off);
            if (ov > bv || (ov == bv && oc < bcol)){ bv = ov; bcol = oc; }
        }
        if (it > 0 && lane == 0) out[it - 1] = bcol;
        #pragma unroll
        for (int q = 0; q < 32; q++){
            if (bcol == q * 64 + lane) vals[q] = -INFINITY;
        }
    }
}

// ---- v = Wa*x, u = (Wb-Wa)*x  -> layout (b,n,o) ----
template<int O>
__global__ __launch_bounds__(256) void uv_gemm_kernel(const float* __restrict__ F, const float* __restrict__ W,
                                                      float* __restrict__ u, float* __restrict__ v, int C){
    const int G = 256 / O;
    const int ROWS = G * 8;
    __shared__ float Wa[O][17], Wd[O][17], Fl[ROWS][17];
    int tid = threadIdx.x;
    int o = tid % O, g = tid / O;
    int row0 = blockIdx.x * ROWS;
    float va[8], ua[8];
    #pragma unroll
    for (int r = 0; r < 8; r++){ va[r] = 0.f; ua[r] = 0.f; }
    for (int c0 = 0; c0 < C; c0 += 16){
        __syncthreads();
        for (int idx = tid; idx < O * 16; idx += 256){
            int oo = idx >> 4, cc = idx & 15; int c = c0 + cc;
            float wa = 0.f, wb = 0.f;
            if (c < C){ wa = W[(size_t)oo * (2 * C) + c]; wb = W[(size_t)oo * (2 * C) + C + c]; }
            Wa[oo][cc] = wa; Wd[oo][cc] = wb - wa;
        }
        for (int idx = tid; idx < ROWS * 16; idx += 256){
            int rr = idx >> 4, cc = idx & 15; int c = c0 + cc;
            Fl[rr][cc] = (c < C) ? F[(size_t)(row0 + rr) * NF + c] : 0.f;
        }
        __syncthreads();
        #pragma unroll
        for (int cc = 0; cc < 16; cc++){
            float wa = Wa[o][cc], wd = Wd[o][cc];
            #pragma unroll
            for (int r = 0; r < 8; r++){
                float f = Fl[g * 8 + r][cc];
                va[r] += wa * f; ua[r] += wd * f;
            }
        }
    }
    #pragma unroll
    for (int r = 0; r < 8; r++){
        size_t row = (size_t)row0 + g * 8 + r;
        v[row * O + o] = va[r];
        u[row * O + o] = ua[r];
    }
}

// ---- gather neighbors: per (b,n,o) max/min of v[nbr] + exact channel stats of h=v[nbr]+u ----
template<int O>
__global__ __launch_bounds__(256) void gather_kernel(const float* __restrict__ v, const float* __restrict__ u,
                                                     const int* __restrict__ idxb, float* __restrict__ mx,
                                                     float* __restrict__ mn, float* __restrict__ ssum,
                                                     float* __restrict__ ssum2){
    const int G = 256 / O;
    int tid = threadIdx.x;
    int o = tid % O, g = tid / O;
    float csum = 0.f, csq = 0.f;
    int stride = gridDim.x * G;
    for (int row = blockIdx.x * G + g; row < NB * NPTS; row += stride){
        int b = row >> 11;
        float uv = u[(size_t)row * O + o];
        const int* ip = idxb + (size_t)row * K;
        float s1 = 0.f, s2 = 0.f, vmax = -INFINITY, vmin = INFINITY;
        for (int j = 0; j < K; j++){
            int nb = ip[j];
            float vv = v[((size_t)(b << 11) + nb) * O + o];
            s1 += vv; s2 += vv * vv;
            vmax = fmaxf(vmax, vv); vmin = fminf(vmin, vv);
        }
        mx[(size_t)row * O + o] = vmax;
        mn[(size_t)row * O + o] = vmin;
        csum += s1 + (float)K * uv;
        csq  += s2 + 2.f * uv * s1 + (float)K * uv * uv;
    }
    __shared__ float red[256];
    red[tid] = csum; __syncthreads();
    if (tid < O){ float t = 0.f; for (int gg = 0; gg < G; gg++) t += red[gg * O + tid]; atomicAdd(&ssum[tid], t); }
    __syncthreads();
    red[tid] = csq; __syncthreads();
    if (tid < O){ float t = 0.f; for (int gg = 0; gg < G; gg++) t += red[gg * O + tid]; atomicAdd(&ssum2[tid], t); }
}

__global__ void finalize_kernel(const float* __restrict__ ssum, const float* __restrict__ ssum2,
                                const float* __restrict__ gg, const float* __restrict__ bb,
                                float* __restrict__ scale, float* __restrict__ shift, int O, float inv_count){
    int o = blockIdx.x * blockDim.x + threadIdx.x;
    if (o >= O) return;
    float mean = ssum[o] * inv_count;
    float var = fmaxf(ssum2[o] * inv_count - mean * mean, 0.f);
    float sc = gg[o] * rsqrtf(var + EPSV);
    scale[o] = sc;
    shift[o] = bb[o] - mean * sc;
}

template<int O>
__global__ __launch_bounds__(256) void apply_kernel(const float* __restrict__ u, const float* __restrict__ mx,
                                                    const float* __restrict__ mn, const float* __restrict__ scale,
                                                    const float* __restrict__ shift, float* __restrict__ F, int coff){
    int gid = blockIdx.x * 256 + threadIdx.x;
    int row = gid / O, o = gid % O;
    float sc = scale[o];
    float sel = sc >= 0.f ? mx[gid] : mn[gid];
    F[(size_t)row * NF + coff + o] = lrelu((u[gid] + sel) * sc + shift[o]);
}

// ---- final: y = W5 @ F, fused per-channel stats + per-(b,o) max/min; y never materialized ----
__global__ __launch_bounds__(256) void final_gemm_kernel(const float* __restrict__ F, const float* __restrict__ W5,
                                                         float* __restrict__ ssum, float* __restrict__ ssum2,
                                                         unsigned* __restrict__ maxk, unsigned* __restrict__ mink){
    __shared__ float Wl[128][17], Fl[64][17];
    int tid = threadIdx.x;
    int tj = tid & 15, ti = tid >> 4;
    int o0 = blockIdx.x * 128, n0 = blockIdx.y * 64, b = blockIdx.z;
    float acc[8][4];
    #pragma unroll
    for (int q = 0; q < 8; q++)
        #pragma unroll
        for (int p = 0; p < 4; p++) acc[q][p] = 0.f;

    for (int c0 = 0; c0 < NF; c0 += 16){
        __syncthreads();
        #pragma unroll
        for (int q = 0; q < 8; q++){
            int idx = tid + q * 256; int r = idx >> 4, cc = idx & 15; int c = c0 + cc;
            Wl[r][cc] = (c < NF) ? W5[(size_t)(o0 + r) * NF + c] : 0.f;
        }
        #pragma unroll
        for (int q = 0; q < 4; q++){
            int idx = tid + q * 256; int r = idx >> 4, cc = idx & 15; int c = c0 + cc;
            Fl[r][cc] = (c < NF) ? F[((size_t)b * NPTS + n0 + r) * NF + c] : 0.f;
        }
        __syncthreads();
        #pragma unroll
        for (int cc = 0; cc < 16; cc++){
            float a0[8], b0[4];
            #pragma unroll
            for (int q = 0; q < 8; q++) a0[q] = Wl[ti * 8 + q][cc];
            #pragma unroll
            for (int p = 0; p < 4; p++) b0[p] = Fl[tj * 4 + p][cc];
            #pragma unroll
            for (int q = 0; q < 8; q++)
                #pragma unroll
                for (int p = 0; p < 4; p++) acc[q][p] += a0[q] * b0[p];
        }
    }
    #pragma unroll
    for (int q = 0; q < 8; q++){
        float s = 0.f, s2 = 0.f, mxv = -INFINITY, mnv = INFINITY;
        #pragma unroll
        for (int p = 0; p < 4; p++){
            float y = acc[q][p];
            s += y; s2 += y * y; mxv = fmaxf(mxv, y); mnv = fminf(mnv, y);
        }
        #pragma unroll
        for (int off = 1; off < 16; off <<= 1){
            s   += __shfl_xor(s, off);
            s2  += __shfl_xor(s2, off);
            mxv  = fmaxf(mxv, __shfl_xor(mxv, off));
            mnv  = fminf(mnv, __shfl_xor(mnv, off));
        }
        if (tj == 0){
            int o = o0 + ti * 8 + q;
            atomicAdd(&ssum[o], s);
            atomicAdd(&ssum2[o], s2);
            atomicMax(&maxk[b * 1024 + o], fkey(mxv));
            atomicMin(&mink[b * 1024 + o], fkey(mnv));
        }
    }
}

__global__ void final_out_kernel(const unsigned* __restrict__ maxk, const unsigned* __restrict__ mink,
                                 const float* __restrict__ ssum, const float* __restrict__ ssum2,
                                 const float* __restrict__ g5, const float* __restrict__ b5,
                                 float* __restrict__ out){
    int gid = blockIdx.x * 256 + threadIdx.x;
    if (gid >= NB * 1024) return;
    int o = gid & 1023;
    const float inv = 1.f / (NB * NPTS);
    float mean = ssum[o] * inv;
    float var = fmaxf(ssum2[o] * inv - mean * mean, 0.f);
    float sc = g5[o] * rsqrtf(var + EPSV);
    float sh = b5[o] - mean * sc;
    float sel = sc >= 0.f ? funkey(maxk[gid]) : funkey(mink[gid]);
    out[gid] = lrelu(sel * sc + sh);
}

extern "C" void kernel_launch(void* const* d_in, const int* in_sizes, int n_in,
                              void* d_out, int out_size, void* d_ws, size_t ws_size,
                              hipStream_t stream){
    (void)in_sizes; (void)n_in; (void)out_size;
    const float* x = (const float*)d_in[0];
    const float* Ws[5] = {(const float*)d_in[1], (const float*)d_in[4], (const float*)d_in[7],
                          (const float*)d_in[10], (const float*)d_in[13]};
    const float* Gs[5] = {(const float*)d_in[2], (const float*)d_in[5], (const float*)d_in[8],
                          (const float*)d_in[11], (const float*)d_in[14]};
    const float* Bs[5] = {(const float*)d_in[3], (const float*)d_in[6], (const float*)d_in[9],
                          (const float*)d_in[12], (const float*)d_in[15]};
    float* out = (float*)d_out;

    char* base = (char*)d_ws;
    size_t off = 0;
    auto alloc = [&](size_t bytes) -> char* {
        char* p = base + off;
        off = (off + bytes + 255) & ~(size_t)255;
        return p;
    };
    float* F     = (float*)alloc((size_t)NB * NPTS * NF * 4);
    float* sq    = (float*)alloc((size_t)NB * NPTS * 4);
    int*   idxb  = (int*)  alloc((size_t)NB * NPTS * K * 4);
    float* u     = (float*)alloc((size_t)NB * NPTS * 128 * 4);
    float* v     = (float*)alloc((size_t)NB * NPTS * 128 * 4);
    float* mx    = (float*)alloc((size_t)NB * NPTS * 128 * 4);
    float* mn    = (float*)alloc((size_t)NB * NPTS * 128 * 4);
    float* ssum  = (float*)alloc(1024 * 4);
    float* ssum2 = (float*)alloc(1024 * 4);
    float* scale = (float*)alloc(1024 * 4);
    float* shift = (float*)alloc(1024 * 4);
    unsigned* maxk = (unsigned*)alloc(NB * 1024 * 4);
    unsigned* mink = (unsigned*)alloc(NB * 1024 * 4);
    float* dist = (float*)(base + off);
    size_t rows_cap = (ws_size > off) ? (ws_size - off) / ((size_t)NPTS * 4) : 64;
    int chunk = (int)((rows_cap / 64) * 64);
    if (chunk > NB * NPTS) chunk = NB * NPTS;
    if (chunk < 64) chunk = 64;

    copy_x_kernel<<<(NB * NPTS + 255) / 256, 256, 0, stream>>>(x, F);

    const int Cs[4] = {3, 67, 131, 195};
    const int Os[4] = {64, 64, 64, 128};
    for (int s = 0; s < 4; s++){
        int C = Cs[s], O = Os[s];
        sqnorm_kernel<<<NB * NPTS / 4, 256, 0, stream>>>(F, sq, C);
        for (int rb = 0; rb < NB * NPTS; rb += chunk){
            int rows = NB * NPTS - rb; if (rows > chunk) rows = chunk;
            dist_kernel<<<dim3(NPTS / 64, rows / 64), 256, 0, stream>>>(F, sq, dist, C, rb);
            topk_kernel<<<rows / 4, 256, 0, stream>>>(dist, idxb, rb);
        }
        hipMemsetAsync(ssum, 0, 1024 * 4, stream);
        hipMemsetAsync(ssum2, 0, 1024 * 4, stream);
        if (O == 64){
            uv_gemm_kernel<64><<<NB * NPTS / 32, 256, 0, stream>>>(F, Ws[s], u, v, C);
            gather_kernel<64><<<256, 256, 0, stream>>>(v, u, idxb, mx, mn, ssum, ssum2);
            finalize_kernel<<<1, 64, 0, stream>>>(ssum, ssum2, Gs[s], Bs[s], scale, shift, 64,
                                                  1.f / ((float)NB * NPTS * K));
            apply_kernel<64><<<NB * NPTS * 64 / 256, 256, 0, stream>>>(u, mx, mn, scale, shift, F, C);
        } else {
            uv_gemm_kernel<128><<<NB * NPTS / 16, 256, 0, stream>>>(F, Ws[s], u, v, C);
            gather_kernel<128><<<256, 256, 0, stream>>>(v, u, idxb, mx, mn, ssum, ssum2);
            finalize_kernel<<<1, 128, 0, stream>>>(ssum, ssum2, Gs[s], Bs[s], scale, shift, 128,
                                                   1.f / ((float)NB * NPTS * K));
            apply_kernel<128><<<NB * NPTS * 128 / 256, 256, 0, stream>>>(u, mx, mn, scale, shift, F, C);
        }
    }

    hipMemsetAsync(ssum, 0, 1024 * 4, stream);
    hipMemsetAsync(ssum2, 0, 1024 * 4, stream);
    hipMemsetAsync(maxk, 0, NB * 1024 * 4, stream);
    hipMemsetAsync(mink, 0xFF, NB * 1024 * 4, stream);
    final_gemm_kernel<<<dim3(1024 / 128, NPTS / 64, NB), 256, 0, stream>>>(F, Ws[4], ssum, ssum2, maxk, mink);
    final_out_kernel<<<NB * 1024 / 256, 256, 0, stream>>>(maxk, mink, ssum, ssum2, Gs[4], Bs[4], out);
}